// Round 5
// baseline (175.370 us; speedup 1.0000x reference)
//
#include <hip/hip_runtime.h>
#include <hip/hip_bf16.h>

// Problem constants
#define BB    16
#define TT    784
#define TPK   832          // padded T for K/V (13*64)
#define TPQ   896          // padded T for Q (7*128)
#define EE    512
#define HH    8
#define DD    64
#define BT    (BB*TT)      // 12544 = 98*128

typedef short short8 __attribute__((ext_vector_type(8)));
typedef short short4v __attribute__((ext_vector_type(4)));
typedef float floatx4 __attribute__((ext_vector_type(4)));

__device__ __forceinline__ short f2bf(float f) {
    unsigned u = __builtin_bit_cast(unsigned, f);
    u += 0x7FFFu + ((u >> 16) & 1u);   // round-to-nearest-even
    return (short)(u >> 16);
}

// async global->LDS, 16 B per lane; LDS dst is wave-uniform base + lane*16
#define ASYNC16(g, l) __builtin_amdgcn_global_load_lds( \
    (const __attribute__((address_space(1))) void*)(g), \
    (__attribute__((address_space(3))) void*)(l), 16, 0, 0)

// ---------------- merged prep: cast_x | pack Wqkv^T | pack Wo^T | zero pads ------------
// grid: [0,3136) cast_x; [3136,3328) pack_wqkv; [3328,3392) pack_wo; [3392,4224) pads
__global__ void prep_kernel(const float* __restrict__ x, short* __restrict__ xb,
                            const float* __restrict__ Wq, const float* __restrict__ Wk,
                            const float* __restrict__ Wv, short* __restrict__ wqkvt,
                            const float* __restrict__ Wo, short* __restrict__ wot,
                            short* __restrict__ Qb, short* __restrict__ Kb, short* __restrict__ Vt)
{
    __shared__ short t[64][65];
    int b = blockIdx.x;
    if (b < 3136) {
        int i = (b * 256 + threadIdx.x) * 8;
        float4 a = *(const float4*)(x + i);
        float4 c = *(const float4*)(x + i + 4);
        short8 o;
        o[0] = f2bf(a.x); o[1] = f2bf(a.y); o[2] = f2bf(a.z); o[3] = f2bf(a.w);
        o[4] = f2bf(c.x); o[5] = f2bf(c.y); o[6] = f2bf(c.z); o[7] = f2bf(c.w);
        *(short8*)(xb + i) = o;
    } else if (b < 3392) {
        const float* W; short* out; int n0, k0;
        if (b < 3328) {
            int tt = b - 3136;               // 0..191
            n0 = (tt % 24) * 64; k0 = (tt / 24) * 64;
            W = (n0 < 512) ? Wq : (n0 < 1024 ? Wk : Wv);
            out = wqkvt;
        } else {
            int tt = b - 3328;               // 0..63
            n0 = (tt % 8) * 64; k0 = (tt / 8) * 64;
            W = Wo; out = wot;
        }
        int nn0 = n0 & 511;
        for (int i = threadIdx.x; i < 4096; i += 256) {
            int r = i >> 6, c = i & 63;
            t[r][c] = f2bf(W[(k0 + r) * 512 + nn0 + c]);
        }
        __syncthreads();
        for (int i = threadIdx.x; i < 4096; i += 256) {
            int nr = i >> 6, kc = i & 63;
            out[(n0 + nr) * 512 + k0 + kc] = t[kc][nr];
        }
    } else {
        // zero pads as short8 chunks: Q rows [784,896), K rows [784,832), Vt cols [784,832)
        int c = (b - 3392) * 256 + threadIdx.x;   // 0..212991
        short8 z = (short8){0,0,0,0,0,0,0,0};
        if (c < 114688) {                          // Q: 896 chunks per bh
            int bh = c / 896, j = c - bh * 896;
            *(short8*)&Qb[(bh * TPQ + TT) * 64 + j * 8] = z;
        } else if (c < 163840) {                   // K: 384 chunks per bh
            int c2 = c - 114688;
            int bh = c2 / 384, j = c2 - bh * 384;
            *(short8*)&Kb[(bh * TPK + TT) * 64 + j * 8] = z;
        } else {                                   // Vt: 384 chunks per bh (6 per d-row)
            int c3 = c - 163840;
            int bh = c3 / 384, j = c3 - bh * 384;
            int d = j / 6, m = j - d * 6;
            *(short8*)&Vt[(bh * 64 + d) * TPK + TT + m * 8] = z;
        }
    }
}

// ---------------- GEMM1: [12544 x 512] @ [512 x 1536] -> scatter Q/K/Vt ----------------
__global__ __launch_bounds__(256, 4) void gemm_qkv_kernel(
    const short* __restrict__ A, const short* __restrict__ Bt,
    const float* __restrict__ bq, const float* __restrict__ bk, const float* __restrict__ bv,
    short* __restrict__ Qb, short* __restrict__ Kb, short* __restrict__ Vt)
{
    __shared__ __align__(16) short smem[16640];
    short* As0 = smem;
    short* Bs0 = smem + 8192;

    const int m0 = blockIdx.x * 128, n0 = blockIdx.y * 128;
    const int tid = threadIdx.x;
    const int lane = tid & 63, w = tid >> 6;
    const int wr = w >> 1, wc = w & 1;
    const int l16 = lane & 15, quad = lane >> 4;

    const short* Ag = A  + (size_t)(m0 + w * 32 + (lane >> 2)) * 512 + (lane & 3) * 8;
    const short* Bg = Bt + (size_t)(n0 + w * 32 + (lane >> 2)) * 512 + (lane & 3) * 8;
    short* Asw = As0 + (w * 32) * 32;
    short* Bsw = Bs0 + (w * 32) * 32;

    floatx4 acc[4][4];
    #pragma unroll
    for (int i = 0; i < 4; i++)
        #pragma unroll
        for (int j = 0; j < 4; j++)
            acc[i][j] = (floatx4){0.f, 0.f, 0.f, 0.f};

    ASYNC16(Ag, Asw);
    ASYNC16(Ag + 16 * 512, Asw + 16 * 32);
    ASYNC16(Bg, Bsw);
    ASYNC16(Bg + 16 * 512, Bsw + 16 * 32);

    for (int it = 0; it < 16; it++) {
        __syncthreads();
        if (it < 15) {
            int nb = (it + 1) & 1;
            int ko = (it + 1) * 32;
            ASYNC16(Ag + ko,            Asw + nb * 4096);
            ASYNC16(Ag + ko + 16 * 512, Asw + nb * 4096 + 16 * 32);
            ASYNC16(Bg + ko,            Bsw + nb * 4096);
            ASYNC16(Bg + ko + 16 * 512, Bsw + nb * 4096 + 16 * 32);
        }
        const short* as = As0 + (it & 1) * 4096;
        const short* bs = Bs0 + (it & 1) * 4096;
        short8 af[4], bf[4];
        #pragma unroll
        for (int i = 0; i < 4; i++) {
            af[i] = *(const short8*)&as[(wr * 64 + i * 16 + l16) * 32 + quad * 8];
            bf[i] = *(const short8*)&bs[(wc * 64 + i * 16 + l16) * 32 + quad * 8];
        }
        #pragma unroll
        for (int mi = 0; mi < 4; mi++)
            #pragma unroll
            for (int ni = 0; ni < 4; ni++)
                acc[mi][ni] = __builtin_amdgcn_mfma_f32_16x16x32_bf16(af[mi], bf[ni], acc[mi][ni], 0, 0, 0);
    }

    const int sel = n0 >> 9;
    if (sel < 2) {
        __syncthreads();   // staging LDS reads done before Ct overwrite
        short* Ct = smem;                // [128][130] bf16
        const float* bias = (sel == 0) ? bq : bk;
        #pragma unroll
        for (int mi = 0; mi < 4; mi++) {
            #pragma unroll
            for (int ni = 0; ni < 4; ni++) {
                int nl = wc * 64 + ni * 16 + l16;
                int nn = (n0 + nl) & 511;
                float b = bias[nn];
                #pragma unroll
                for (int r = 0; r < 4; r++) {
                    float v = acc[mi][ni][r] + b;
                    if (sel == 0) v *= 0.125f;
                    Ct[(wr * 64 + mi * 16 + quad * 4 + r) * 130 + nl] = f2bf(v);
                }
            }
        }
        __syncthreads();
        short* dst = (sel == 0) ? Qb : Kb;
        const int tp = (sel == 0) ? TPQ : TPK;
        int nl = lane * 2;
        int nn = (n0 + nl) & 511;
        int hh = nn >> 6, dd = nn & 63;
        #pragma unroll 4
        for (int rr = 0; rr < 32; rr++) {
            int ml = w * 32 + rr;
            int m = m0 + ml;
            int bb = m / TT, t = m - bb * TT;
            unsigned pv = *(const unsigned*)&Ct[ml * 130 + nl];
            *(unsigned*)&dst[((bb * HH + hh) * tp + t) * 64 + dd] = pv;
        }
    } else {
        // V: direct 8B stores — acc rows are 4 consecutive t (4-aligned, never straddle b)
        #pragma unroll
        for (int mi = 0; mi < 4; mi++) {
            int m = m0 + wr * 64 + mi * 16 + quad * 4;
            int bb = m / TT, t = m - bb * TT;
            #pragma unroll
            for (int ni = 0; ni < 4; ni++) {
                int nn = (n0 + wc * 64 + ni * 16 + l16) & 511;
                int hh = nn >> 6, dd = nn & 63;
                float b = bv[nn];
                short4v pv;
                #pragma unroll
                for (int r = 0; r < 4; r++) pv[r] = f2bf(acc[mi][ni][r] + b);
                *(short4v*)&Vt[((size_t)(bb * HH + hh) * 64 + dd) * TPK + t] = pv;
            }
        }
    }
}

// ---------------- attention: 128-q-tiles, no-max softmax, MFMA row-sums ----------------
#define LK 72  // row stride (shorts): 144B, 16B-aligned
__global__ __launch_bounds__(256, 2) void attn_kernel(
    const short* __restrict__ Qb, const short* __restrict__ Kb, const short* __restrict__ Vt,
    short* __restrict__ ctx)
{
    // grid: g = (6-qt)*128 + bh  -> qt=6 (longest) first; bh%8 fixed per XCD slot
    const int g = blockIdx.x;
    const int qt = 6 - (g >> 7);
    const int bh = g & 127;
    const int bb = bh >> 3, hh = bh & 7;
    const int tid = threadIdx.x;
    const int lane = tid & 63, w = tid >> 6;
    const int l16 = lane & 15, quad = lane >> 4;

    __shared__ short Ks[2][64 * LK];   // [key][d]
    __shared__ short Vs[2][64 * LK];   // [d][key]
    __shared__ short Ps[128 * LK];     // [q][key], wave-private 32-row slices, XOR-16 swizzled

    const int srow = tid >> 3;          // 0..31
    const int sc8 = (tid & 7) * 8;
    const short* Kbase = Kb + (size_t)(bh * TPK) * 64;
    const short* Vbase = Vt + (size_t)(bh * 64) * TPK;

    short8 kreg[2], vreg[2];
    auto load_tile = [&](int kt) {
        #pragma unroll
        for (int p = 0; p < 2; p++) {
            int row = srow + p * 32;
            kreg[p] = *(const short8*)(Kbase + (kt * 64 + row) * 64 + sc8);
            vreg[p] = *(const short8*)(Vbase + row * TPK + kt * 64 + sc8);
        }
    };
    auto store_tile = [&](int b) {
        #pragma unroll
        for (int p = 0; p < 2; p++) {
            int row = srow + p * 32;
            *(short8*)&Ks[b][row * LK + sc8] = kreg[p];
            *(short8*)&Vs[b][row * LK + sc8] = vreg[p];
        }
    };

    // Q fragments (A-layout): wave w owns q rows [w*32, w*32+32) of the tile
    const int q0 = qt * 128;
    short8 qa[2][2];
    #pragma unroll
    for (int mi = 0; mi < 2; mi++) {
        const short* Qrow = Qb + (size_t)(bh * TPQ + q0 + w * 32 + mi * 16 + l16) * 64;
        qa[mi][0] = *(const short8*)(Qrow + quad * 8);
        qa[mi][1] = *(const short8*)(Qrow + 32 + quad * 8);
    }

    floatx4 accO[2][4];
    floatx4 accL[2];
    #pragma unroll
    for (int mi = 0; mi < 2; mi++) {
        accL[mi] = (floatx4){0.f, 0.f, 0.f, 0.f};
        #pragma unroll
        for (int dt = 0; dt < 4; dt++) accO[mi][dt] = (floatx4){0.f, 0.f, 0.f, 0.f};
    }

    short8 ones8;
    #pragma unroll
    for (int j = 0; j < 8; j++) ones8[j] = (short)0x3F80;   // bf16 1.0

    const int pswz  = (quad >> 1) * 16;        // write-col swizzle (row bit3 = quad bit1)
    const int prswz = ((l16 >> 3) & 1) * 16;   // read-col swizzle (row bit3 = l16 bit3)

    const int kt_end = (2 * qt + 2 < 13) ? (2 * qt + 2) : 13;

    load_tile(0);
    store_tile(0);

    for (int kt = 0; kt < kt_end; kt++) {
        const int cb = kt & 1;
        if (kt + 1 < kt_end) load_tile(kt + 1);   // prefetch into regs, overlapped
        __syncthreads();                           // staging for kt visible

        // P = exp(Q K^T) for both m-frags; write to swizzled wave-private Ps rows
        #pragma unroll
        for (int mi = 0; mi < 2; mi++) {
            const int qr0 = q0 + w * 32 + mi * 16;
            float p[4][4];
            #pragma unroll
            for (int ni = 0; ni < 4; ni++) {
                const int kbase = kt * 64 + ni * 16;
                if (kbase > qr0 + 15) {            // wave-uniform: fully masked
                    #pragma unroll
                    for (int r = 0; r < 4; r++) p[ni][r] = 0.f;
                    continue;
                }
                short8 kb0 = *(short8*)&Ks[cb][(ni * 16 + l16) * LK + quad * 8];
                short8 kb1 = *(short8*)&Ks[cb][(ni * 16 + l16) * LK + 32 + quad * 8];
                floatx4 z = (floatx4){0.f, 0.f, 0.f, 0.f};
                z = __builtin_amdgcn_mfma_f32_16x16x32_bf16(qa[mi][0], kb0, z, 0, 0, 0);
                z = __builtin_amdgcn_mfma_f32_16x16x32_bf16(qa[mi][1], kb1, z, 0, 0, 0);
                if (kbase == qr0) {                // partial: mask key > q within frag
                    #pragma unroll
                    for (int r = 0; r < 4; r++)
                        if (l16 > quad * 4 + r) z[r] = -1e30f;
                }
                #pragma unroll
                for (int r = 0; r < 4; r++) p[ni][r] = __expf(z[r]);
            }
            short* Pw = &Ps[(w * 32 + mi * 16 + quad * 4) * LK];
            #pragma unroll
            for (int ni = 0; ni < 4; ni++) {
                int col = (ni * 16 + l16) ^ pswz;
                #pragma unroll
                for (int r = 0; r < 4; r++)
                    Pw[r * LK + col] = (short)(__builtin_bit_cast(unsigned, p[ni][r]) >> 16);
            }
        }

        // O += P V ; L += P 1  (same-wave RAW on Ps, no barrier)
        #pragma unroll
        for (int kk = 0; kk < 2; kk++) {
            const int kb32 = kt * 64 + kk * 32;
            if (kb32 > q0 + w * 32 + 31) continue;     // wave-uniform: both frags zero
            short8 vb[4];
            #pragma unroll
            for (int dt = 0; dt < 4; dt++)
                vb[dt] = *(short8*)&Vs[cb][(dt * 16 + l16) * LK + kk * 32 + quad * 8];
            #pragma unroll
            for (int mi = 0; mi < 2; mi++) {
                if (kb32 > q0 + w * 32 + mi * 16 + 15) continue;
                short8 pa = *(short8*)&Ps[(w * 32 + mi * 16 + l16) * LK + ((kk * 32 + quad * 8) ^ prswz)];
                accL[mi] = __builtin_amdgcn_mfma_f32_16x16x32_bf16(pa, ones8, accL[mi], 0, 0, 0);
                #pragma unroll
                for (int dt = 0; dt < 4; dt++)
                    accO[mi][dt] = __builtin_amdgcn_mfma_f32_16x16x32_bf16(pa, vb[dt], accO[mi][dt], 0, 0, 0);
            }
        }

        if (kt + 1 < kt_end) store_tile((kt + 1) & 1);
    }

    // epilogue: ctx[b*T+t][h*64+d] bf16 ; accL cols all equal row-sum l
    #pragma unroll
    for (int mi = 0; mi < 2; mi++) {
        float inv_l[4];
        #pragma unroll
        for (int r = 0; r < 4; r++) inv_l[r] = 1.f / accL[mi][r];
        #pragma unroll
        for (int dt = 0; dt < 4; dt++)
            #pragma unroll
            for (int r = 0; r < 4; r++) {
                int qg = q0 + w * 32 + mi * 16 + quad * 4 + r;
                if (qg < TT)
                    ctx[(size_t)(bb * TT + qg) * 512 + hh * 64 + dt * 16 + l16] =
                        f2bf(accO[mi][dt][r] * inv_l[r]);
            }
    }
}

// ---------------- GEMM2: ctx @ Wo + bo -> out fp32 ----------------
__global__ __launch_bounds__(256, 4) void gemm_out_kernel(
    const short* __restrict__ A, const short* __restrict__ Bt,
    const float* __restrict__ bo, float* __restrict__ out)
{
    __shared__ __align__(16) short smem[16384];
    short* As0 = smem;
    short* Bs0 = smem + 8192;

    const int m0 = blockIdx.x * 128, n0 = blockIdx.y * 128;
    const int tid = threadIdx.x;
    const int lane = tid & 63, w = tid >> 6;
    const int wr = w >> 1, wc = w & 1;
    const int l16 = lane & 15, quad = lane >> 4;

    const short* Ag = A  + (size_t)(m0 + w * 32 + (lane >> 2)) * 512 + (lane & 3) * 8;
    const short* Bg = Bt + (size_t)(n0 + w * 32 + (lane >> 2)) * 512 + (lane & 3) * 8;
    short* Asw = As0 + (w * 32) * 32;
    short* Bsw = Bs0 + (w * 32) * 32;

    floatx4 acc[4][4];
    #pragma unroll
    for (int i = 0; i < 4; i++)
        #pragma unroll
        for (int j = 0; j < 4; j++)
            acc[i][j] = (floatx4){0.f, 0.f, 0.f, 0.f};

    ASYNC16(Ag, Asw);
    ASYNC16(Ag + 16 * 512, Asw + 16 * 32);
    ASYNC16(Bg, Bsw);
    ASYNC16(Bg + 16 * 512, Bsw + 16 * 32);

    for (int it = 0; it < 16; it++) {
        __syncthreads();
        if (it < 15) {
            int nb = (it + 1) & 1;
            int ko = (it + 1) * 32;
            ASYNC16(Ag + ko,            Asw + nb * 4096);
            ASYNC16(Ag + ko + 16 * 512, Asw + nb * 4096 + 16 * 32);
            ASYNC16(Bg + ko,            Bsw + nb * 4096);
            ASYNC16(Bg + ko + 16 * 512, Bsw + nb * 4096 + 16 * 32);
        }
        const short* as = As0 + (it & 1) * 4096;
        const short* bs = Bs0 + (it & 1) * 4096;
        short8 af[4], bf[4];
        #pragma unroll
        for (int i = 0; i < 4; i++) {
            af[i] = *(const short8*)&as[(wr * 64 + i * 16 + l16) * 32 + quad * 8];
            bf[i] = *(const short8*)&bs[(wc * 64 + i * 16 + l16) * 32 + quad * 8];
        }
        #pragma unroll
        for (int mi = 0; mi < 4; mi++)
            #pragma unroll
            for (int ni = 0; ni < 4; ni++)
                acc[mi][ni] = __builtin_amdgcn_mfma_f32_16x16x32_bf16(af[mi], bf[ni], acc[mi][ni], 0, 0, 0);
    }

    #pragma unroll
    for (int mi = 0; mi < 4; mi++) {
        #pragma unroll
        for (int ni = 0; ni < 4; ni++) {
            int n = n0 + wc * 64 + ni * 16 + l16;
            float bias = bo[n];
            #pragma unroll
            for (int r = 0; r < 4; r++) {
                int m = m0 + wr * 64 + mi * 16 + quad * 4 + r;
                out[(size_t)m * 512 + n] = acc[mi][ni][r] + bias;
            }
        }
    }
}

extern "C" void kernel_launch(void* const* d_in, const int* in_sizes, int n_in,
                              void* d_out, int out_size, void* d_ws, size_t ws_size,
                              hipStream_t stream) {
    const float* x  = (const float*)d_in[0];
    const float* Wq = (const float*)d_in[1];
    const float* bq = (const float*)d_in[2];
    const float* Wk = (const float*)d_in[3];
    const float* bk = (const float*)d_in[4];
    const float* Wv = (const float*)d_in[5];
    const float* bv = (const float*)d_in[6];
    const float* Wo = (const float*)d_in[7];
    const float* bo = (const float*)d_in[8];
    float* out = (float*)d_out;

    char* ws = (char*)d_ws;
    size_t off = 0;
    auto alloc = [&](size_t bytes) -> void* {
        void* p = ws + off;
        off += (bytes + 255) & ~(size_t)255;
        return p;
    };
    short* xb    = (short*)alloc((size_t)BT * EE * 2);        // x bf16
    short* wqkvt = (short*)alloc((size_t)1536 * 512 * 2);     // Wqkv^T bf16
    short* wot   = (short*)alloc((size_t)512 * 512 * 2);      // Wo^T bf16
    short* Qb    = (short*)alloc((size_t)BB * HH * TPQ * DD * 2);
    short* Kb    = (short*)alloc((size_t)BB * HH * TPK * DD * 2);
    short* Vtb   = (short*)alloc((size_t)BB * HH * DD * TPK * 2);
    short* ctxb  = (short*)alloc((size_t)BT * EE * 2);

    prep_kernel<<<4224, 256, 0, stream>>>(x, xb, Wq, Wk, Wv, wqkvt, Wo, wot, Qb, Kb, Vtb);
    gemm_qkv_kernel<<<dim3(98, 12), 256, 0, stream>>>(xb, wqkvt, bq, bk, bv, Qb, Kb, Vtb);
    attn_kernel<<<896, 256, 0, stream>>>(Qb, Kb, Vtb, ctxb);
    gemm_out_kernel<<<dim3(98, 4), 256, 0, stream>>>(ctxb, wot, bo, out);
}

// Round 6
// 172.617 us; speedup vs baseline: 1.0159x; 1.0159x over previous
//
#include <hip/hip_runtime.h>
#include <hip/hip_bf16.h>

// Problem constants
#define BB    16
#define TT    784
#define TPK   832          // padded T for K/V (13*64)
#define TPQ   896          // padded T for Q (kept from r5; attn reads <=832)
#define EE    512
#define HH    8
#define DD    64
#define BT    (BB*TT)      // 12544 = 49*256

typedef short short8 __attribute__((ext_vector_type(8)));
typedef short short4v __attribute__((ext_vector_type(4)));
typedef float floatx4 __attribute__((ext_vector_type(4)));

__device__ __forceinline__ short f2bf(float f) {
    unsigned u = __builtin_bit_cast(unsigned, f);
    u += 0x7FFFu + ((u >> 16) & 1u);   // round-to-nearest-even
    return (short)(u >> 16);
}

// async global->LDS, 16 B per lane; LDS dst is wave-uniform base + lane*16
#define ASYNC16(g, l) __builtin_amdgcn_global_load_lds( \
    (const __attribute__((address_space(1))) void*)(g), \
    (__attribute__((address_space(3))) void*)(l), 16, 0, 0)

// ---------------- merged prep: cast_x | pack Wqkv^T | pack Wo^T | zero pads ------------
// grid: [0,3136) cast_x; [3136,3328) pack_wqkv; [3328,3392) pack_wo; [3392,4224) pads
__global__ void prep_kernel(const float* __restrict__ x, short* __restrict__ xb,
                            const float* __restrict__ Wq, const float* __restrict__ Wk,
                            const float* __restrict__ Wv, short* __restrict__ wqkvt,
                            const float* __restrict__ Wo, short* __restrict__ wot,
                            short* __restrict__ Qb, short* __restrict__ Kb, short* __restrict__ Vt)
{
    __shared__ short t[64][65];
    int b = blockIdx.x;
    if (b < 3136) {
        int i = (b * 256 + threadIdx.x) * 8;
        float4 a = *(const float4*)(x + i);
        float4 c = *(const float4*)(x + i + 4);
        short8 o;
        o[0] = f2bf(a.x); o[1] = f2bf(a.y); o[2] = f2bf(a.z); o[3] = f2bf(a.w);
        o[4] = f2bf(c.x); o[5] = f2bf(c.y); o[6] = f2bf(c.z); o[7] = f2bf(c.w);
        *(short8*)(xb + i) = o;
    } else if (b < 3392) {
        const float* W; short* out; int n0, k0;
        if (b < 3328) {
            int tt = b - 3136;               // 0..191
            n0 = (tt % 24) * 64; k0 = (tt / 24) * 64;
            W = (n0 < 512) ? Wq : (n0 < 1024 ? Wk : Wv);
            out = wqkvt;
        } else {
            int tt = b - 3328;               // 0..63
            n0 = (tt % 8) * 64; k0 = (tt / 8) * 64;
            W = Wo; out = wot;
        }
        int nn0 = n0 & 511;
        for (int i = threadIdx.x; i < 4096; i += 256) {
            int r = i >> 6, c = i & 63;
            t[r][c] = f2bf(W[(k0 + r) * 512 + nn0 + c]);
        }
        __syncthreads();
        for (int i = threadIdx.x; i < 4096; i += 256) {
            int nr = i >> 6, kc = i & 63;
            out[(n0 + nr) * 512 + k0 + kc] = t[kc][nr];
        }
    } else {
        // zero pads as short8 chunks: Q rows [784,896), K rows [784,832), Vt cols [784,832)
        int c = (b - 3392) * 256 + threadIdx.x;   // 0..212991
        short8 z = (short8){0,0,0,0,0,0,0,0};
        if (c < 114688) {                          // Q: 896 chunks per bh
            int bh = c / 896, j = c - bh * 896;
            *(short8*)&Qb[(bh * TPQ + TT) * 64 + j * 8] = z;
        } else if (c < 163840) {                   // K: 384 chunks per bh
            int c2 = c - 114688;
            int bh = c2 / 384, j = c2 - bh * 384;
            *(short8*)&Kb[(bh * TPK + TT) * 64 + j * 8] = z;
        } else {                                   // Vt: 384 chunks per bh (6 per d-row)
            int c3 = c - 163840;
            int bh = c3 / 384, j = c3 - bh * 384;
            int d = j / 6, m = j - d * 6;
            *(short8*)&Vt[(bh * 64 + d) * TPK + TT + m * 8] = z;
        }
    }
}

// ---------------- GEMM1: 256x128 tiles, [12544 x 512] @ [512 x 1536] -> Q/K/Vt --------
// wave w: m-rows [w*64, w*64+64) x all 128 n; acc 4x8; 6 async stages + 32 MFMA per iter
__global__ __launch_bounds__(256, 2) void gemm_qkv_kernel(
    const short* __restrict__ A, const short* __restrict__ Bt,
    const float* __restrict__ bq, const float* __restrict__ bk, const float* __restrict__ bv,
    short* __restrict__ Qb, short* __restrict__ Kb, short* __restrict__ Vt)
{
    __shared__ __align__(16) short smem[24576];   // 49152 B: A dbuf 2x8192, B dbuf 2x4096
    short* As0 = smem;                            // [2][8192]  (256 x 32)
    short* Bs0 = smem + 16384;                    // [2][4096]  (128 x 32)

    const int m0 = blockIdx.x * 256, n0 = blockIdx.y * 128;
    const int tid = threadIdx.x;
    const int lane = tid & 63, w = tid >> 6;
    const int l16 = lane & 15, quad = lane >> 4;

    // staging: A wave w -> rows [w*64, w*64+64) in 4 chunks of 16 rows
    const short* Ag = A  + (size_t)(m0 + w * 64 + (lane >> 2)) * 512 + (lane & 3) * 8;
    const short* Bg = Bt + (size_t)(n0 + w * 32 + (lane >> 2)) * 512 + (lane & 3) * 8;
    short* Asw = As0 + w * 64 * 32;   // wave-uniform base, buffer 0
    short* Bsw = Bs0 + w * 32 * 32;

    floatx4 acc[4][8];
    #pragma unroll
    for (int i = 0; i < 4; i++)
        #pragma unroll
        for (int j = 0; j < 8; j++)
            acc[i][j] = (floatx4){0.f, 0.f, 0.f, 0.f};

    // prologue: stage buffer 0
    #pragma unroll
    for (int p = 0; p < 4; p++) ASYNC16(Ag + p * 16 * 512, Asw + p * 512);
    ASYNC16(Bg, Bsw);
    ASYNC16(Bg + 16 * 512, Bsw + 512);

    for (int it = 0; it < 16; it++) {
        __syncthreads();   // current buffer staged; prev compute done
        if (it < 15) {
            int nb = (it + 1) & 1;
            int ko = (it + 1) * 32;
            #pragma unroll
            for (int p = 0; p < 4; p++)
                ASYNC16(Ag + ko + p * 16 * 512, Asw + nb * 8192 + p * 512);
            ASYNC16(Bg + ko,            Bsw + nb * 4096);
            ASYNC16(Bg + ko + 16 * 512, Bsw + nb * 4096 + 512);
        }
        const short* as = As0 + (it & 1) * 8192;
        const short* bs = Bs0 + (it & 1) * 4096;
        short8 af[4], bf[8];
        #pragma unroll
        for (int i = 0; i < 4; i++)
            af[i] = *(const short8*)&as[(w * 64 + i * 16 + l16) * 32 + quad * 8];
        #pragma unroll
        for (int j = 0; j < 8; j++)
            bf[j] = *(const short8*)&bs[(j * 16 + l16) * 32 + quad * 8];
        #pragma unroll
        for (int mi = 0; mi < 4; mi++)
            #pragma unroll
            for (int ni = 0; ni < 8; ni++)
                acc[mi][ni] = __builtin_amdgcn_mfma_f32_16x16x32_bf16(af[mi], bf[ni], acc[mi][ni], 0, 0, 0);
    }

    const int sel = n0 >> 9;   // 0=Q, 1=K, 2=V (uniform per block)
    if (sel == 2) {
        // V: direct 8B stores — acc rows are 4 consecutive t (4-aligned, never straddle b)
        #pragma unroll
        for (int mi = 0; mi < 4; mi++) {
            int m = m0 + w * 64 + mi * 16 + quad * 4;
            int bb = m / TT, t = m - bb * TT;
            #pragma unroll
            for (int ni = 0; ni < 8; ni++) {
                int nn = (n0 + ni * 16 + l16) & 511;
                int hh = nn >> 6, dd = nn & 63;
                float b = bv[nn];
                short4v pv;
                #pragma unroll
                for (int r = 0; r < 4; r++) pv[r] = f2bf(acc[mi][ni][r] + b);
                *(short4v*)&Vt[((size_t)(bb * HH + hh) * 64 + dd) * TPK + t] = pv;
            }
        }
    } else {
        // Q/K: two-pass epilogue through Ct[128][130] (reuses staging LDS)
        short* Ct = smem;
        const float* bias = (sel == 0) ? bq : bk;
        short* dst = (sel == 0) ? Qb : Kb;
        const int tp = (sel == 0) ? TPQ : TPK;
        const int nlc = lane * 2;
        const int nnc = (n0 + nlc) & 511;
        const int hhc = nnc >> 6, ddc = nnc & 63;
        #pragma unroll
        for (int h = 0; h < 2; h++) {
            __syncthreads();   // h=0: staging reads done; h=1: prev store pass done
            if ((w >> 1) == h) {
                int wl = w & 1;
                #pragma unroll
                for (int mi = 0; mi < 4; mi++) {
                    #pragma unroll
                    for (int ni = 0; ni < 8; ni++) {
                        int nl = ni * 16 + l16;
                        int nn = (n0 + nl) & 511;
                        float b = bias[nn];
                        #pragma unroll
                        for (int r = 0; r < 4; r++) {
                            float v = acc[mi][ni][r] + b;
                            if (sel == 0) v *= 0.125f;
                            Ct[(wl * 64 + mi * 16 + quad * 4 + r) * 130 + nl] = f2bf(v);
                        }
                    }
                }
            }
            __syncthreads();
            #pragma unroll 4
            for (int rr = 0; rr < 32; rr++) {
                int ml = w * 32 + rr;
                int m = m0 + h * 128 + ml;
                int bb = m / TT, t = m - bb * TT;
                unsigned pv = *(const unsigned*)&Ct[ml * 130 + nlc];
                *(unsigned*)&dst[((bb * HH + hhc) * tp + t) * 64 + ddc] = pv;
            }
        }
    }
}

// ---------------- attention: 64-q-tiles, no-max softmax, MFMA row-sums (r4 version) ----
#define LK 72  // row stride (shorts): 144B, 16B-aligned
__global__ __launch_bounds__(256, 3) void attn_kernel(
    const short* __restrict__ Qb, const short* __restrict__ Kb, const short* __restrict__ Vt,
    short* __restrict__ ctx)
{
    // flat grid: id = ((12-qt)*16 + bb)*8 + hh  -> same XCD slice per (b,h); qt=12 first
    const int g = blockIdx.x;
    const int low = g & 7, rest = g >> 3;
    const int qt = 12 - (rest >> 4);
    const int bh = ((rest & 15) << 3) | low;
    const int bb = bh >> 3, hh = bh & 7;
    const int tid = threadIdx.x;
    const int lane = tid & 63, w = tid >> 6;
    const int l16 = lane & 15, quad = lane >> 4;

    __shared__ short Ks[2][64 * LK];   // [key][d]
    __shared__ short Vs[2][64 * LK];   // [d][key]
    __shared__ short Ps[64 * LK];      // [q][key], wave-private 16-row slices, XOR-16 swizzled

    const int srow = tid >> 3;          // 0..31
    const int sc8 = (tid & 7) * 8;
    const short* Kbase = Kb + (size_t)(bh * TPK) * 64;
    const short* Vbase = Vt + (size_t)(bh * 64) * TPK;

    short8 kreg[2], vreg[2];
    auto load_tile = [&](int kt) {
        #pragma unroll
        for (int p = 0; p < 2; p++) {
            int row = srow + p * 32;
            kreg[p] = *(const short8*)(Kbase + (kt * 64 + row) * 64 + sc8);
            vreg[p] = *(const short8*)(Vbase + row * TPK + kt * 64 + sc8);
        }
    };
    auto store_tile = [&](int b) {
        #pragma unroll
        for (int p = 0; p < 2; p++) {
            int row = srow + p * 32;
            *(short8*)&Ks[b][row * LK + sc8] = kreg[p];
            *(short8*)&Vs[b][row * LK + sc8] = vreg[p];
        }
    };

    // Q fragments (A-layout): row = w*16 + l16, k = d
    const short* Qrow = Qb + (size_t)(bh * TPQ + qt * 64 + w * 16 + l16) * 64;
    short8 qa0 = *(const short8*)(Qrow + quad * 8);
    short8 qa1 = *(const short8*)(Qrow + 32 + quad * 8);

    floatx4 accO[4];
    floatx4 accL = (floatx4){0.f, 0.f, 0.f, 0.f};
    #pragma unroll
    for (int dt = 0; dt < 4; dt++) accO[dt] = (floatx4){0.f, 0.f, 0.f, 0.f};

    short8 ones8;
    #pragma unroll
    for (int j = 0; j < 8; j++) ones8[j] = (short)0x3F80;   // bf16 1.0

    const int pswz  = (quad >> 1) * 16;        // write-col swizzle (row bit3 = quad bit1)
    const int prswz = ((l16 >> 3) & 1) * 16;   // read-col swizzle (row bit3 = l16 bit3)
    short* Pw = &Ps[(w * 16 + quad * 4) * LK];

    load_tile(0);
    store_tile(0);

    for (int kt = 0; kt <= qt; kt++) {
        const int cb = kt & 1;
        const bool diag = (kt == qt);
        if (kt < qt) load_tile(kt + 1);      // prefetch into regs, overlapped
        __syncthreads();                      // staging for kt visible

        // P = exp(Q K^T); no max subtraction (scores ~N(0,1), bounded ≪ overflow)
        float p[4][4];
        #pragma unroll
        for (int ni = 0; ni < 4; ni++) {
            if (diag && ni > w) {             // wave-uniform: fully masked fragment
                #pragma unroll
                for (int r = 0; r < 4; r++) p[ni][r] = 0.f;
                continue;
            }
            short8 kb0 = *(short8*)&Ks[cb][(ni * 16 + l16) * LK + quad * 8];
            short8 kb1 = *(short8*)&Ks[cb][(ni * 16 + l16) * LK + 32 + quad * 8];
            floatx4 z = (floatx4){0.f, 0.f, 0.f, 0.f};
            z = __builtin_amdgcn_mfma_f32_16x16x32_bf16(qa0, kb0, z, 0, 0, 0);
            z = __builtin_amdgcn_mfma_f32_16x16x32_bf16(qa1, kb1, z, 0, 0, 0);
            if (diag && ni == w) {            // partial mask on diagonal fragment
                #pragma unroll
                for (int r = 0; r < 4; r++)
                    if (l16 > quad * 4 + r) z[r] = -1e30f;
            }
            #pragma unroll
            for (int r = 0; r < 4; r++) p[ni][r] = __expf(z[r]);
        }

        // write P (truncated bf16) to wave-private swizzled Ps rows; same-wave RAW
        #pragma unroll
        for (int ni = 0; ni < 4; ni++) {
            int col = (ni * 16 + l16) ^ pswz;
            #pragma unroll
            for (int r = 0; r < 4; r++)
                Pw[r * LK + col] = (short)(__builtin_bit_cast(unsigned, p[ni][r]) >> 16);
        }

        // O += P V ; L += P 1 (row sums via constant-ones B fragment)
        #pragma unroll
        for (int kk = 0; kk < 2; kk++) {
            if (diag && (kk * 32 > w * 16 + 15)) continue;   // wave-uniform: P==0 there
            short8 pa = *(short8*)&Ps[(w * 16 + l16) * LK + ((kk * 32 + quad * 8) ^ prswz)];
            accL = __builtin_amdgcn_mfma_f32_16x16x32_bf16(pa, ones8, accL, 0, 0, 0);
            #pragma unroll
            for (int dt = 0; dt < 4; dt++) {
                short8 vb = *(short8*)&Vs[cb][(dt * 16 + l16) * LK + kk * 32 + quad * 8];
                accO[dt] = __builtin_amdgcn_mfma_f32_16x16x32_bf16(pa, vb, accO[dt], 0, 0, 0);
            }
        }

        if (kt < qt) store_tile((kt + 1) & 1);   // safe: all waves past this iter's barrier
    }

    // epilogue: ctx[b*T+t][h*64+d] bf16 ; accL cols all equal row-sum l
    float inv_l[4];
    #pragma unroll
    for (int r = 0; r < 4; r++) inv_l[r] = 1.f / accL[r];
    #pragma unroll
    for (int dt = 0; dt < 4; dt++)
        #pragma unroll
        for (int r = 0; r < 4; r++) {
            int qg = qt * 64 + w * 16 + quad * 4 + r;
            if (qg < TT)
                ctx[(size_t)(bb * TT + qg) * 512 + hh * 64 + dt * 16 + l16] = f2bf(accO[dt][r] * inv_l[r]);
        }
}

// ---------------- GEMM2: ctx @ Wo + bo -> out fp32 ----------------
__global__ __launch_bounds__(256, 4) void gemm_out_kernel(
    const short* __restrict__ A, const short* __restrict__ Bt,
    const float* __restrict__ bo, float* __restrict__ out)
{
    __shared__ __align__(16) short smem[16384];
    short* As0 = smem;
    short* Bs0 = smem + 8192;

    const int m0 = blockIdx.x * 128, n0 = blockIdx.y * 128;
    const int tid = threadIdx.x;
    const int lane = tid & 63, w = tid >> 6;
    const int wr = w >> 1, wc = w & 1;
    const int l16 = lane & 15, quad = lane >> 4;

    const short* Ag = A  + (size_t)(m0 + w * 32 + (lane >> 2)) * 512 + (lane & 3) * 8;
    const short* Bg = Bt + (size_t)(n0 + w * 32 + (lane >> 2)) * 512 + (lane & 3) * 8;
    short* Asw = As0 + (w * 32) * 32;
    short* Bsw = Bs0 + (w * 32) * 32;

    floatx4 acc[4][4];
    #pragma unroll
    for (int i = 0; i < 4; i++)
        #pragma unroll
        for (int j = 0; j < 4; j++)
            acc[i][j] = (floatx4){0.f, 0.f, 0.f, 0.f};

    ASYNC16(Ag, Asw);
    ASYNC16(Ag + 16 * 512, Asw + 16 * 32);
    ASYNC16(Bg, Bsw);
    ASYNC16(Bg + 16 * 512, Bsw + 16 * 32);

    for (int it = 0; it < 16; it++) {
        __syncthreads();
        if (it < 15) {
            int nb = (it + 1) & 1;
            int ko = (it + 1) * 32;
            ASYNC16(Ag + ko,            Asw + nb * 4096);
            ASYNC16(Ag + ko + 16 * 512, Asw + nb * 4096 + 16 * 32);
            ASYNC16(Bg + ko,            Bsw + nb * 4096);
            ASYNC16(Bg + ko + 16 * 512, Bsw + nb * 4096 + 16 * 32);
        }
        const short* as = As0 + (it & 1) * 4096;
        const short* bs = Bs0 + (it & 1) * 4096;
        short8 af[4], bf[4];
        #pragma unroll
        for (int i = 0; i < 4; i++) {
            af[i] = *(const short8*)&as[(wr * 64 + i * 16 + l16) * 32 + quad * 8];
            bf[i] = *(const short8*)&bs[(wc * 64 + i * 16 + l16) * 32 + quad * 8];
        }
        #pragma unroll
        for (int mi = 0; mi < 4; mi++)
            #pragma unroll
            for (int ni = 0; ni < 4; ni++)
                acc[mi][ni] = __builtin_amdgcn_mfma_f32_16x16x32_bf16(af[mi], bf[ni], acc[mi][ni], 0, 0, 0);
    }

    #pragma unroll
    for (int mi = 0; mi < 4; mi++) {
        #pragma unroll
        for (int ni = 0; ni < 4; ni++) {
            int n = n0 + wc * 64 + ni * 16 + l16;
            float bias = bo[n];
            #pragma unroll
            for (int r = 0; r < 4; r++) {
                int m = m0 + wr * 64 + mi * 16 + quad * 4 + r;
                out[(size_t)m * 512 + n] = acc[mi][ni][r] + bias;
            }
        }
    }
}

extern "C" void kernel_launch(void* const* d_in, const int* in_sizes, int n_in,
                              void* d_out, int out_size, void* d_ws, size_t ws_size,
                              hipStream_t stream) {
    const float* x  = (const float*)d_in[0];
    const float* Wq = (const float*)d_in[1];
    const float* bq = (const float*)d_in[2];
    const float* Wk = (const float*)d_in[3];
    const float* bk = (const float*)d_in[4];
    const float* Wv = (const float*)d_in[5];
    const float* bv = (const float*)d_in[6];
    const float* Wo = (const float*)d_in[7];
    const float* bo = (const float*)d_in[8];
    float* out = (float*)d_out;

    char* ws = (char*)d_ws;
    size_t off = 0;
    auto alloc = [&](size_t bytes) -> void* {
        void* p = ws + off;
        off += (bytes + 255) & ~(size_t)255;
        return p;
    };
    short* xb    = (short*)alloc((size_t)BT * EE * 2);        // x bf16
    short* wqkvt = (short*)alloc((size_t)1536 * 512 * 2);     // Wqkv^T bf16
    short* wot   = (short*)alloc((size_t)512 * 512 * 2);      // Wo^T bf16
    short* Qb    = (short*)alloc((size_t)BB * HH * TPQ * DD * 2);
    short* Kb    = (short*)alloc((size_t)BB * HH * TPK * DD * 2);
    short* Vtb   = (short*)alloc((size_t)BB * HH * DD * TPK * 2);
    short* ctxb  = (short*)alloc((size_t)BT * EE * 2);

    prep_kernel<<<4224, 256, 0, stream>>>(x, xb, Wq, Wk, Wv, wqkvt, Wo, wot, Qb, Kb, Vtb);
    gemm_qkv_kernel<<<dim3(49, 12), 256, 0, stream>>>(xb, wqkvt, bq, bk, bv, Qb, Kb, Vtb);
    attn_kernel<<<1664, 256, 0, stream>>>(Qb, Kb, Vtb, ctxb);
    gemm_out_kernel<<<dim3(98, 4), 256, 0, stream>>>(ctxb, wot, bo, out);
}

// Round 7
// 165.348 us; speedup vs baseline: 1.0606x; 1.0440x over previous
//
#include <hip/hip_runtime.h>
#include <hip/hip_bf16.h>

// Problem constants
#define BB    16
#define TT    784
#define TPK   832          // padded T for K/V (13*64)
#define TPQ   896          // padded T for Q
#define EE    512
#define HH    8
#define DD    64
#define BT    (BB*TT)      // 12544 = 98*128

typedef short short8 __attribute__((ext_vector_type(8)));
typedef short short4v __attribute__((ext_vector_type(4)));
typedef float floatx4 __attribute__((ext_vector_type(4)));

__device__ __forceinline__ short f2bf(float f) {
    unsigned u = __builtin_bit_cast(unsigned, f);
    u += 0x7FFFu + ((u >> 16) & 1u);   // round-to-nearest-even
    return (short)(u >> 16);
}

// ---------------- merged prep: cast_x | pack Wqkv^T | pack Wo^T | zero pads ------------
// grid: [0,3136) cast_x; [3136,3328) pack_wqkv; [3328,3392) pack_wo; [3392,4224) pads
__global__ void prep_kernel(const float* __restrict__ x, short* __restrict__ xb,
                            const float* __restrict__ Wq, const float* __restrict__ Wk,
                            const float* __restrict__ Wv, short* __restrict__ wqkvt,
                            const float* __restrict__ Wo, short* __restrict__ wot,
                            short* __restrict__ Qb, short* __restrict__ Kb, short* __restrict__ Vt)
{
    __shared__ short t[64][65];
    int b = blockIdx.x;
    if (b < 3136) {
        int i = (b * 256 + threadIdx.x) * 8;
        float4 a = *(const float4*)(x + i);
        float4 c = *(const float4*)(x + i + 4);
        short8 o;
        o[0] = f2bf(a.x); o[1] = f2bf(a.y); o[2] = f2bf(a.z); o[3] = f2bf(a.w);
        o[4] = f2bf(c.x); o[5] = f2bf(c.y); o[6] = f2bf(c.z); o[7] = f2bf(c.w);
        *(short8*)(xb + i) = o;
    } else if (b < 3392) {
        const float* W; short* out; int n0, k0;
        if (b < 3328) {
            int tt = b - 3136;               // 0..191
            n0 = (tt % 24) * 64; k0 = (tt / 24) * 64;
            W = (n0 < 512) ? Wq : (n0 < 1024 ? Wk : Wv);
            out = wqkvt;
        } else {
            int tt = b - 3328;               // 0..63
            n0 = (tt % 8) * 64; k0 = (tt / 8) * 64;
            W = Wo; out = wot;
        }
        int nn0 = n0 & 511;
        for (int i = threadIdx.x; i < 4096; i += 256) {
            int r = i >> 6, c = i & 63;
            t[r][c] = f2bf(W[(k0 + r) * 512 + nn0 + c]);
        }
        __syncthreads();
        for (int i = threadIdx.x; i < 4096; i += 256) {
            int nr = i >> 6, kc = i & 63;
            out[(n0 + nr) * 512 + k0 + kc] = t[kc][nr];
        }
    } else {
        // zero pads as short8 chunks: Q rows [784,896), K rows [784,832), Vt cols [784,832)
        int c = (b - 3392) * 256 + threadIdx.x;   // 0..212991
        short8 z = (short8){0,0,0,0,0,0,0,0};
        if (c < 114688) {                          // Q: 896 chunks per bh
            int bh = c / 896, j = c - bh * 896;
            *(short8*)&Qb[(bh * TPQ + TT) * 64 + j * 8] = z;
        } else if (c < 163840) {                   // K: 384 chunks per bh
            int c2 = c - 114688;
            int bh = c2 / 384, j = c2 - bh * 384;
            *(short8*)&Kb[(bh * TPK + TT) * 64 + j * 8] = z;
        } else {                                   // Vt: 384 chunks per bh (6 per d-row)
            int c3 = c - 163840;
            int bh = c3 / 384, j = c3 - bh * 384;
            int d = j / 6, m = j - d * 6;
            *(short8*)&Vt[(bh * 64 + d) * TPK + TT + m * 8] = z;
        }
    }
}

// ---------------- GEMM1: 128x128 tiles, register-prefetch staging ----------------
// Staging loads go to VGPRs (no LDS side-effect) so __syncthreads needs no vmcnt(0)
// drain; the vmcnt wait lands at the ds_write AFTER the MFMA block -> latency hidden.
__global__ __launch_bounds__(256, 4) void gemm_qkv_kernel(
    const short* __restrict__ A, const short* __restrict__ Bt,
    const float* __restrict__ bq, const float* __restrict__ bk, const float* __restrict__ bv,
    short* __restrict__ Qb, short* __restrict__ Kb, short* __restrict__ Vt)
{
    __shared__ __align__(16) short smem[16640];   // staging dbuf 16384 shorts; Ct 16640
    short* As0 = smem;                             // [2][4096]  (128 x 32)
    short* Bs0 = smem + 8192;                      // [2][4096]

    const int m0 = blockIdx.x * 128, n0 = blockIdx.y * 128;
    const int tid = threadIdx.x;
    const int lane = tid & 63, w = tid >> 6;
    const int wr = w >> 1, wc = w & 1;
    const int l16 = lane & 15, quad = lane >> 4;

    // staging map: lane i of wave w -> row w*32 + i/4 (+0/+16), col (i%4)*8
    const int srow = w * 32 + (lane >> 2);
    const int scol = (lane & 3) * 8;
    const short* Ag = A  + (size_t)(m0 + srow) * 512 + scol;
    const short* Bg = Bt + (size_t)(n0 + srow) * 512 + scol;
    const int soff = srow * 32 + scol;             // LDS offset within a buffer

    short8 areg[2], breg[2];
    auto load_regs = [&](int it) {
        int ko = it * 32;
        areg[0] = *(const short8*)(Ag + ko);
        areg[1] = *(const short8*)(Ag + ko + 16 * 512);
        breg[0] = *(const short8*)(Bg + ko);
        breg[1] = *(const short8*)(Bg + ko + 16 * 512);
    };
    auto store_regs = [&](int b) {
        *(short8*)&As0[b * 4096 + soff]            = areg[0];
        *(short8*)&As0[b * 4096 + soff + 16 * 32]  = areg[1];
        *(short8*)&Bs0[b * 4096 + soff]            = breg[0];
        *(short8*)&Bs0[b * 4096 + soff + 16 * 32]  = breg[1];
    };

    floatx4 acc[4][4];
    #pragma unroll
    for (int i = 0; i < 4; i++)
        #pragma unroll
        for (int j = 0; j < 4; j++)
            acc[i][j] = (floatx4){0.f, 0.f, 0.f, 0.f};

    load_regs(0);
    store_regs(0);

    for (int it = 0; it < 16; it++) {
        if (it < 15) load_regs(it + 1);   // issue global loads; waited at store_regs below
        __syncthreads();                   // buf[it&1] staged for all
        const short* as = As0 + (it & 1) * 4096;
        const short* bs = Bs0 + (it & 1) * 4096;
        short8 af[4], bf[4];
        #pragma unroll
        for (int i = 0; i < 4; i++) {
            af[i] = *(const short8*)&as[(wr * 64 + i * 16 + l16) * 32 + quad * 8];
            bf[i] = *(const short8*)&bs[(wc * 64 + i * 16 + l16) * 32 + quad * 8];
        }
        #pragma unroll
        for (int mi = 0; mi < 4; mi++)
            #pragma unroll
            for (int ni = 0; ni < 4; ni++)
                acc[mi][ni] = __builtin_amdgcn_mfma_f32_16x16x32_bf16(af[mi], bf[ni], acc[mi][ni], 0, 0, 0);
        if (it < 15) store_regs((it + 1) & 1);   // other waves' reads of that buf ended pre-barrier
    }

    const int sel = n0 >> 9;   // 0=Q, 1=K, 2=V (uniform per block)
    if (sel == 2) {
        // V: direct 8B stores — acc rows are 4 consecutive t (4-aligned, never straddle b)
        #pragma unroll
        for (int mi = 0; mi < 4; mi++) {
            int m = m0 + wr * 64 + mi * 16 + quad * 4;
            int bb = m / TT, t = m - bb * TT;
            #pragma unroll
            for (int ni = 0; ni < 4; ni++) {
                int nn = (n0 + wc * 64 + ni * 16 + l16) & 511;
                int hh = nn >> 6, dd = nn & 63;
                float b = bv[nn];
                short4v pv;
                #pragma unroll
                for (int r = 0; r < 4; r++) pv[r] = f2bf(acc[mi][ni][r] + b);
                *(short4v*)&Vt[((size_t)(bb * HH + hh) * 64 + dd) * TPK + t] = pv;
            }
        }
    } else {
        __syncthreads();   // staging LDS reads done before Ct overwrite
        short* Ct = smem;  // [128][130] bf16
        const float* bias = (sel == 0) ? bq : bk;
        #pragma unroll
        for (int mi = 0; mi < 4; mi++) {
            #pragma unroll
            for (int ni = 0; ni < 4; ni++) {
                int nl = wc * 64 + ni * 16 + l16;
                int nn = (n0 + nl) & 511;
                float b = bias[nn];
                #pragma unroll
                for (int r = 0; r < 4; r++) {
                    float v = acc[mi][ni][r] + b;
                    if (sel == 0) v *= 0.125f;
                    Ct[(wr * 64 + mi * 16 + quad * 4 + r) * 130 + nl] = f2bf(v);
                }
            }
        }
        __syncthreads();
        short* dst = (sel == 0) ? Qb : Kb;
        const int tp = (sel == 0) ? TPQ : TPK;
        int nl = lane * 2;
        int nn = (n0 + nl) & 511;
        int hh = nn >> 6, dd = nn & 63;
        #pragma unroll 4
        for (int rr = 0; rr < 32; rr++) {
            int ml = w * 32 + rr;
            int m = m0 + ml;
            int bb = m / TT, t = m - bb * TT;
            unsigned pv = *(const unsigned*)&Ct[ml * 130 + nl];
            *(unsigned*)&dst[((bb * HH + hh) * tp + t) * 64 + dd] = pv;
        }
    }
}

// ---------------- attention: 64-q-tiles, no-max softmax, MFMA row-sums ----------------
#define LK 72  // row stride (shorts): 144B, 16B-aligned
__global__ __launch_bounds__(256, 3) void attn_kernel(
    const short* __restrict__ Qb, const short* __restrict__ Kb, const short* __restrict__ Vt,
    short* __restrict__ ctx)
{
    // flat grid: id = ((12-qt)*16 + bb)*8 + hh  -> same XCD slice per (b,h); qt=12 first
    const int g = blockIdx.x;
    const int low = g & 7, rest = g >> 3;
    const int qt = 12 - (rest >> 4);
    const int bh = ((rest & 15) << 3) | low;
    const int bb = bh >> 3, hh = bh & 7;
    const int tid = threadIdx.x;
    const int lane = tid & 63, w = tid >> 6;
    const int l16 = lane & 15, quad = lane >> 4;

    __shared__ short Ks[2][64 * LK];   // [key][d]
    __shared__ short Vs[2][64 * LK];   // [d][key]
    __shared__ short Ps[64 * LK];      // [q][key], wave-private 16-row slices, XOR-16 swizzled

    const int srow = tid >> 3;          // 0..31
    const int sc8 = (tid & 7) * 8;
    const short* Kbase = Kb + (size_t)(bh * TPK) * 64;
    const short* Vbase = Vt + (size_t)(bh * 64) * TPK;

    short8 kreg[2], vreg[2];
    auto load_tile = [&](int kt) {
        #pragma unroll
        for (int p = 0; p < 2; p++) {
            int row = srow + p * 32;
            kreg[p] = *(const short8*)(Kbase + (kt * 64 + row) * 64 + sc8);
            vreg[p] = *(const short8*)(Vbase + row * TPK + kt * 64 + sc8);
        }
    };
    auto store_tile = [&](int b) {
        #pragma unroll
        for (int p = 0; p < 2; p++) {
            int row = srow + p * 32;
            *(short8*)&Ks[b][row * LK + sc8] = kreg[p];
            *(short8*)&Vs[b][row * LK + sc8] = vreg[p];
        }
    };

    // Q fragments (A-layout): row = w*16 + l16, k = d
    const short* Qrow = Qb + (size_t)(bh * TPQ + qt * 64 + w * 16 + l16) * 64;
    short8 qa0 = *(const short8*)(Qrow + quad * 8);
    short8 qa1 = *(const short8*)(Qrow + 32 + quad * 8);

    floatx4 accO[4];
    floatx4 accL = (floatx4){0.f, 0.f, 0.f, 0.f};
    #pragma unroll
    for (int dt = 0; dt < 4; dt++) accO[dt] = (floatx4){0.f, 0.f, 0.f, 0.f};

    short8 ones8;
    #pragma unroll
    for (int j = 0; j < 8; j++) ones8[j] = (short)0x3F80;   // bf16 1.0

    const int pswz  = (quad >> 1) * 16;        // write-col swizzle (row bit3 = quad bit1)
    const int prswz = ((l16 >> 3) & 1) * 16;   // read-col swizzle (row bit3 = l16 bit3)
    short* Pw = &Ps[(w * 16 + quad * 4) * LK];

    load_tile(0);
    store_tile(0);

    for (int kt = 0; kt <= qt; kt++) {
        const int cb = kt & 1;
        const bool diag = (kt == qt);
        if (kt < qt) load_tile(kt + 1);      // prefetch into regs, overlapped
        __syncthreads();                      // staging for kt visible

        // P = exp(Q K^T); no max subtraction (scores ~N(0,1), bounded ≪ overflow)
        float p[4][4];
        #pragma unroll
        for (int ni = 0; ni < 4; ni++) {
            if (diag && ni > w) {             // wave-uniform: fully masked fragment
                #pragma unroll
                for (int r = 0; r < 4; r++) p[ni][r] = 0.f;
                continue;
            }
            short8 kb0 = *(short8*)&Ks[cb][(ni * 16 + l16) * LK + quad * 8];
            short8 kb1 = *(short8*)&Ks[cb][(ni * 16 + l16) * LK + 32 + quad * 8];
            floatx4 z = (floatx4){0.f, 0.f, 0.f, 0.f};
            z = __builtin_amdgcn_mfma_f32_16x16x32_bf16(qa0, kb0, z, 0, 0, 0);
            z = __builtin_amdgcn_mfma_f32_16x16x32_bf16(qa1, kb1, z, 0, 0, 0);
            if (diag && ni == w) {            // partial mask on diagonal fragment
                #pragma unroll
                for (int r = 0; r < 4; r++)
                    if (l16 > quad * 4 + r) z[r] = -1e30f;
            }
            #pragma unroll
            for (int r = 0; r < 4; r++) p[ni][r] = __expf(z[r]);
        }

        // write P (truncated bf16) to wave-private swizzled Ps rows; same-wave RAW
        #pragma unroll
        for (int ni = 0; ni < 4; ni++) {
            int col = (ni * 16 + l16) ^ pswz;
            #pragma unroll
            for (int r = 0; r < 4; r++)
                Pw[r * LK + col] = (short)(__builtin_bit_cast(unsigned, p[ni][r]) >> 16);
        }

        // O += P V ; L += P 1 (row sums via constant-ones B fragment)
        #pragma unroll
        for (int kk = 0; kk < 2; kk++) {
            if (diag && (kk * 32 > w * 16 + 15)) continue;   // wave-uniform: P==0 there
            short8 pa = *(short8*)&Ps[(w * 16 + l16) * LK + ((kk * 32 + quad * 8) ^ prswz)];
            accL = __builtin_amdgcn_mfma_f32_16x16x32_bf16(pa, ones8, accL, 0, 0, 0);
            #pragma unroll
            for (int dt = 0; dt < 4; dt++) {
                short8 vb = *(short8*)&Vs[cb][(dt * 16 + l16) * LK + kk * 32 + quad * 8];
                accO[dt] = __builtin_amdgcn_mfma_f32_16x16x32_bf16(pa, vb, accO[dt], 0, 0, 0);
            }
        }

        if (kt < qt) store_tile((kt + 1) & 1);   // safe: all waves past this iter's barrier
    }

    // epilogue: ctx[b*T+t][h*64+d] bf16 ; accL cols all equal row-sum l
    float inv_l[4];
    #pragma unroll
    for (int r = 0; r < 4; r++) inv_l[r] = 1.f / accL[r];
    #pragma unroll
    for (int dt = 0; dt < 4; dt++)
        #pragma unroll
        for (int r = 0; r < 4; r++) {
            int qg = qt * 64 + w * 16 + quad * 4 + r;
            if (qg < TT)
                ctx[(size_t)(bb * TT + qg) * 512 + hh * 64 + dt * 16 + l16] = f2bf(accO[dt][r] * inv_l[r]);
        }
}

// ---------------- GEMM2: ctx @ Wo + bo -> out fp32, register-prefetch staging ----------
__global__ __launch_bounds__(256, 4) void gemm_out_kernel(
    const short* __restrict__ A, const short* __restrict__ Bt,
    const float* __restrict__ bo, float* __restrict__ out)
{
    __shared__ __align__(16) short smem[16384];
    short* As0 = smem;
    short* Bs0 = smem + 8192;

    const int m0 = blockIdx.x * 128, n0 = blockIdx.y * 128;
    const int tid = threadIdx.x;
    const int lane = tid & 63, w = tid >> 6;
    const int wr = w >> 1, wc = w & 1;
    const int l16 = lane & 15, quad = lane >> 4;

    const int srow = w * 32 + (lane >> 2);
    const int scol = (lane & 3) * 8;
    const short* Ag = A  + (size_t)(m0 + srow) * 512 + scol;
    const short* Bg = Bt + (size_t)(n0 + srow) * 512 + scol;
    const int soff = srow * 32 + scol;

    short8 areg[2], breg[2];
    auto load_regs = [&](int it) {
        int ko = it * 32;
        areg[0] = *(const short8*)(Ag + ko);
        areg[1] = *(const short8*)(Ag + ko + 16 * 512);
        breg[0] = *(const short8*)(Bg + ko);
        breg[1] = *(const short8*)(Bg + ko + 16 * 512);
    };
    auto store_regs = [&](int b) {
        *(short8*)&As0[b * 4096 + soff]            = areg[0];
        *(short8*)&As0[b * 4096 + soff + 16 * 32]  = areg[1];
        *(short8*)&Bs0[b * 4096 + soff]            = breg[0];
        *(short8*)&Bs0[b * 4096 + soff + 16 * 32]  = breg[1];
    };

    floatx4 acc[4][4];
    #pragma unroll
    for (int i = 0; i < 4; i++)
        #pragma unroll
        for (int j = 0; j < 4; j++)
            acc[i][j] = (floatx4){0.f, 0.f, 0.f, 0.f};

    load_regs(0);
    store_regs(0);

    for (int it = 0; it < 16; it++) {
        if (it < 15) load_regs(it + 1);
        __syncthreads();
        const short* as = As0 + (it & 1) * 4096;
        const short* bs = Bs0 + (it & 1) * 4096;
        short8 af[4], bf[4];
        #pragma unroll
        for (int i = 0; i < 4; i++) {
            af[i] = *(const short8*)&as[(wr * 64 + i * 16 + l16) * 32 + quad * 8];
            bf[i] = *(const short8*)&bs[(wc * 64 + i * 16 + l16) * 32 + quad * 8];
        }
        #pragma unroll
        for (int mi = 0; mi < 4; mi++)
            #pragma unroll
            for (int ni = 0; ni < 4; ni++)
                acc[mi][ni] = __builtin_amdgcn_mfma_f32_16x16x32_bf16(af[mi], bf[ni], acc[mi][ni], 0, 0, 0);
        if (it < 15) store_regs((it + 1) & 1);
    }

    #pragma unroll
    for (int mi = 0; mi < 4; mi++) {
        #pragma unroll
        for (int ni = 0; ni < 4; ni++) {
            int n = n0 + wc * 64 + ni * 16 + l16;
            float bias = bo[n];
            #pragma unroll
            for (int r = 0; r < 4; r++) {
                int m = m0 + wr * 64 + mi * 16 + quad * 4 + r;
                out[(size_t)m * 512 + n] = acc[mi][ni][r] + bias;
            }
        }
    }
}

extern "C" void kernel_launch(void* const* d_in, const int* in_sizes, int n_in,
                              void* d_out, int out_size, void* d_ws, size_t ws_size,
                              hipStream_t stream) {
    const float* x  = (const float*)d_in[0];
    const float* Wq = (const float*)d_in[1];
    const float* bq = (const float*)d_in[2];
    const float* Wk = (const float*)d_in[3];
    const float* bk = (const float*)d_in[4];
    const float* Wv = (const float*)d_in[5];
    const float* bv = (const float*)d_in[6];
    const float* Wo = (const float*)d_in[7];
    const float* bo = (const float*)d_in[8];
    float* out = (float*)d_out;

    char* ws = (char*)d_ws;
    size_t off = 0;
    auto alloc = [&](size_t bytes) -> void* {
        void* p = ws + off;
        off += (bytes + 255) & ~(size_t)255;
        return p;
    };
    short* xb    = (short*)alloc((size_t)BT * EE * 2);        // x bf16
    short* wqkvt = (short*)alloc((size_t)1536 * 512 * 2);     // Wqkv^T bf16
    short* wot   = (short*)alloc((size_t)512 * 512 * 2);      // Wo^T bf16
    short* Qb    = (short*)alloc((size_t)BB * HH * TPQ * DD * 2);
    short* Kb    = (short*)alloc((size_t)BB * HH * TPK * DD * 2);
    short* Vtb   = (short*)alloc((size_t)BB * HH * DD * TPK * 2);
    short* ctxb  = (short*)alloc((size_t)BT * EE * 2);

    prep_kernel<<<4224, 256, 0, stream>>>(x, xb, Wq, Wk, Wv, wqkvt, Wo, wot, Qb, Kb, Vtb);
    gemm_qkv_kernel<<<dim3(98, 12), 256, 0, stream>>>(xb, wqkvt, bq, bk, bv, Qb, Kb, Vtb);
    attn_kernel<<<1664, 256, 0, stream>>>(Qb, Kb, Vtb, ctxb);
    gemm_out_kernel<<<dim3(98, 4), 256, 0, stream>>>(ctxb, wot, bo, out);
}